// Round 2
// baseline (1088.040 us; speedup 1.0000x reference)
//
#include <hip/hip_runtime.h>
#include <hip/hip_bf16.h>
#include <stdint.h>

#define NTOK 49
#define DIM 128
#define SCALE 0.17677669529663689f  /* 32^-0.5 */

typedef __attribute__((ext_vector_type(4))) float f32x4;
typedef __attribute__((ext_vector_type(2))) unsigned int u32x2;
typedef __attribute__((ext_vector_type(4))) unsigned int u32x4;
typedef __attribute__((ext_vector_type(8))) short bfrag;   // 8 bf16 = 4 VGPRs
typedef __attribute__((ext_vector_type(4))) short s16x4;   // 4 bf16 = 8B
typedef __attribute__((ext_vector_type(4))) float facc;    // 4 f32 accum

#define MFMA16(A,B,C) __builtin_amdgcn_mfma_f32_16x16x32_bf16(A,B,C,0,0,0)

__device__ __forceinline__ unsigned pk2bf(float a, float b) {  // RNE pack 2xbf16
    unsigned ua = __builtin_bit_cast(unsigned, a);
    unsigned ub = __builtin_bit_cast(unsigned, b);
    ua = ua + 0x7fffu + ((ua >> 16) & 1u);
    ub = ub + 0x7fffu + ((ub >> 16) & 1u);
    return (ua >> 16) | (ub & 0xffff0000u);
}
__device__ __forceinline__ short f2bf(float a) {
    unsigned ua = __builtin_bit_cast(unsigned, a);
    ua = ua + 0x7fffu + ((ua >> 16) & 1u);
    return (short)(ua >> 16);
}
__device__ __forceinline__ float bf2f(short s) {
    unsigned u = ((unsigned)(unsigned short)s) << 16;
    return __builtin_bit_cast(float, u);
}
// XOR swizzle (T2/G4): spread rows across 16B slots; 256B / 128B row strides
__device__ __forceinline__ int sw256(int row, int cb) { return row * 256 + (cb ^ ((row & 7) << 4)); }
__device__ __forceinline__ int sw128(int row, int cb) { return row * 128 + (cb ^ ((row & 7) << 4)); }

// x fragment direct from global: tok row, 8 fp32 at colf, convert bf16, zero pads
__device__ __forceinline__ bfrag load_x_frag(const float* __restrict__ xw, int tok, int colf) {
    const float* p = xw + (size_t)(tok < NTOK ? tok : NTOK - 1) * DIM + colf;
    f32x4 a = *(const f32x4*)p;
    f32x4 b = *(const f32x4*)(p + 4);
    u32x4 w;
    w.x = pk2bf(a.x, a.y); w.y = pk2bf(a.z, a.w);
    w.z = pk2bf(b.x, b.y); w.w = pk2bf(b.z, b.w);
    if (tok >= NTOK) w = (u32x4){0, 0, 0, 0};
    return __builtin_bit_cast(bfrag, w);
}

// ws layout (shorts): Wq 0 | Wk 16384 | Wv 32768 | Wp 49152 | RB[4][64][64] 65536
//                     | cmb[1024][4][64][64] 81920  (only if ws_size permits)
__global__ void prep_w(const float* __restrict__ Wq, const float* __restrict__ Wk,
                       const float* __restrict__ Wv, const float* __restrict__ Wp,
                       const float* __restrict__ relb, short* __restrict__ ws)
{
    int t = blockIdx.x * 256 + threadIdx.x;
    if (t < 16384) {
        ws[t]         = f2bf(Wq[t]);
        ws[16384 + t] = f2bf(Wk[t]);
        ws[32768 + t] = f2bf(Wv[t]);
        ws[49152 + t] = f2bf(Wp[t]);
        int h = t >> 12, r = (t >> 6) & 63, m = t & 63;
        float v = 0.f;
        if (r < NTOK && m < NTOK) {
            int idx = ((r / 7 - m / 7) + 6) * 13 + ((r % 7) - (m % 7) + 6);
            v = relb[idx * 4 + h];
        }
        ws[65536 + t] = f2bf(v);
    }
}

// combined bias: cmb[w][h][r][m] = mask[w][r][m] + rel_bias[h][r][m], -1e30 at pads
__global__ void prep_cmb(const float* __restrict__ mask, const float* __restrict__ relb,
                         short* __restrict__ cmb)
{
    int t = blockIdx.x * 256 + threadIdx.x;           // 16.7M entries
    int m = t & 63, r = (t >> 6) & 63, h = (t >> 12) & 3, w = t >> 14;
    float v = -1e30f;
    if (r < NTOK && m < NTOK) {
        int idx = ((r / 7 - m / 7) + 6) * 13 + ((r % 7) - (m % 7) + 6);
        v = mask[w * (NTOK * NTOK) + r * NTOK + m] + relb[idx * 4 + h];
    }
    cmb[t] = f2bf(v);
}

// One block per window; 4 waves; wave = head in attention phases.
// LDS 48KB: [0,16K) q | [16K,32K) k  (q∪k -> P[4][8KB] -> att in [0,16K))
//           [32K,48K) vT[128][64]
template<bool USE_CMB>
__global__ __launch_bounds__(256, 3) void swin_fwd(
    const float* __restrict__ x, const float* __restrict__ mask,
    const float* __restrict__ bq, const float* __restrict__ bk,
    const float* __restrict__ bv, const float* __restrict__ bp,
    const short* __restrict__ wq, const short* __restrict__ wk,
    const short* __restrict__ wv, const short* __restrict__ wp,
    const short* __restrict__ rb, const short* __restrict__ cmb,
    float* __restrict__ out)
{
    extern __shared__ char smem[];
    char* qbuf  = smem;
    char* kbuf  = smem + 16384;
    char* vtbuf = smem + 32768;

    const int win = blockIdx.x;
    const int tid = threadIdx.x;
    const int wid = tid >> 6;
    const int lane = tid & 63;
    const int l16 = lane & 15;
    const int lg = lane >> 4;
    const float* xw = x + (size_t)win * (NTOK * DIM);

    // ---- phase 1 (QKV): qT/kT GEMM D[o][tok] -> row-major q,k in LDS;
    //      v standard GEMM D[tok][o] -> vT in LDS. x fragments direct from global.
    {
        bfrag aq[2][4], ak[2][4];
        float bqv[2][4], bkv[2][4];
        #pragma unroll
        for (int mt = 0; mt < 2; ++mt) {
            #pragma unroll
            for (int ks = 0; ks < 4; ++ks) {
                int o = wid * 32 + mt * 16 + l16;
                int c = ks * 32 + lg * 8;
                aq[mt][ks] = *(const bfrag*)(wq + o * 128 + c);
                ak[mt][ks] = *(const bfrag*)(wk + o * 128 + c);
            }
            #pragma unroll
            for (int j = 0; j < 4; ++j) {
                int o = wid * 32 + mt * 16 + lg * 4 + j;
                bqv[mt][j] = bq[o];
                bkv[mt][j] = bk[o];
            }
        }
        #pragma unroll
        for (int nt = 0; nt < 4; ++nt) {
            bfrag bx[4];
            #pragma unroll
            for (int ks = 0; ks < 4; ++ks)
                bx[ks] = load_x_frag(xw, nt * 16 + l16, ks * 32 + lg * 8);
            facc accq[2] = {{0,0,0,0},{0,0,0,0}};
            facc acck[2] = {{0,0,0,0},{0,0,0,0}};
            #pragma unroll
            for (int ks = 0; ks < 4; ++ks)
                #pragma unroll
                for (int mt = 0; mt < 2; ++mt) {
                    accq[mt] = MFMA16(aq[mt][ks], bx[ks], accq[mt]);
                    acck[mt] = MFMA16(ak[mt][ks], bx[ks], acck[mt]);
                }
            int tok = nt * 16 + l16;
            #pragma unroll
            for (int mt = 0; mt < 2; ++mt) {
                int o0 = wid * 32 + mt * 16 + lg * 4;
                u32x2 wq2, wk2;
                wq2.x = pk2bf((accq[mt][0] + bqv[mt][0]) * SCALE, (accq[mt][1] + bqv[mt][1]) * SCALE);
                wq2.y = pk2bf((accq[mt][2] + bqv[mt][2]) * SCALE, (accq[mt][3] + bqv[mt][3]) * SCALE);
                wk2.x = pk2bf(acck[mt][0] + bkv[mt][0], acck[mt][1] + bkv[mt][1]);
                wk2.y = pk2bf(acck[mt][2] + bkv[mt][2], acck[mt][3] + bkv[mt][3]);
                *(u32x2*)(qbuf + sw256(tok, o0 * 2)) = wq2;
                *(u32x2*)(kbuf + sw256(tok, o0 * 2)) = wk2;
            }
        }
        // v: wave strip tok in [wid*16, wid*16+16)
        bfrag axf[4];
        #pragma unroll
        for (int ks = 0; ks < 4; ++ks)
            axf[ks] = load_x_frag(xw, wid * 16 + l16, ks * 32 + lg * 8);
        facc accv[8];
        #pragma unroll
        for (int nt = 0; nt < 8; ++nt) accv[nt] = (facc){0, 0, 0, 0};
        #pragma unroll
        for (int ks = 0; ks < 4; ++ks)
            #pragma unroll
            for (int nt = 0; nt < 8; ++nt) {
                bfrag bw = *(const bfrag*)(wv + (nt * 16 + l16) * 128 + ks * 32 + lg * 8);
                accv[nt] = MFMA16(axf[ks], bw, accv[nt]);
            }
        #pragma unroll
        for (int nt = 0; nt < 8; ++nt) {
            int o = nt * 16 + l16;
            float bvo = bv[o];
            int tok0 = wid * 16 + lg * 4;
            u32x2 w;
            w.x = pk2bf(accv[nt][0] + bvo, accv[nt][1] + bvo);
            w.y = pk2bf(accv[nt][2] + bvo, accv[nt][3] + bvo);
            *(u32x2*)(vtbuf + sw128(o, tok0 * 2)) = w;
        }
    }
    __syncthreads();   // B1: QKV stores -> S reads

    // ---- phase 2: QK^T (S^T = k·qT), head = wid
    facc s[4][4];   // s[mt][rt]: D[m][r]
    {
        bfrag ka[4], qb[4];
        int cb = (wid * 32 + lg * 8) * 2;
        #pragma unroll
        for (int t = 0; t < 4; ++t) {
            ka[t] = *(const bfrag*)(kbuf + sw256(t * 16 + l16, cb));
            qb[t] = *(const bfrag*)(qbuf + sw256(t * 16 + l16, cb));
        }
        #pragma unroll
        for (int mt = 0; mt < 4; ++mt)
            #pragma unroll
            for (int rt = 0; rt < 4; ++rt) {
                facc z = {0, 0, 0, 0};
                s[mt][rt] = MFMA16(ka[mt], qb[rt], z);
            }
    }
    __syncthreads();   // B2: q/k reads done -> P may overwrite q∪k

    // ---- phase 3: softmax over key m (bias from cmb or rb+mask); P wave-private
    float rs4[4];
    {
        char* pbuf = smem + wid * 8192;
        const short* cw = cmb + (((size_t)(win & 1023) * 4 + wid) << 12);
        const short* rbh = rb + wid * 4096;
        const float* mw = mask + (size_t)(win & 1023) * (NTOK * NTOK);
        #pragma unroll
        for (int rt = 0; rt < 4; ++rt) {
            int r = rt * 16 + l16;
            float lgt[4][4];
            float mx = -3e38f;
            #pragma unroll
            for (int mt = 0; mt < 4; ++mt) {
                if (USE_CMB) {
                    s16x4 b4 = *(const s16x4*)(cw + r * 64 + mt * 16 + lg * 4);
                    #pragma unroll
                    for (int j = 0; j < 4; ++j) {
                        float v = s[mt][rt][j] + bf2f(b4[j]);
                        lgt[mt][j] = v;
                        mx = fmaxf(mx, v);
                    }
                } else {
                    #pragma unroll
                    for (int j = 0; j < 4; ++j) {
                        int m = mt * 16 + lg * 4 + j;
                        float bias = (r < NTOK && m < NTOK)
                                   ? bf2f(rbh[r * 64 + m]) + mw[r * 49 + m] : -1e30f;
                        float v = s[mt][rt][j] + bias;
                        lgt[mt][j] = v;
                        mx = fmaxf(mx, v);
                    }
                }
            }
            mx = fmaxf(mx, __shfl_xor(mx, 16));
            mx = fmaxf(mx, __shfl_xor(mx, 32));
            float sum = 0.f;
            u32x2 pw[4];
            #pragma unroll
            for (int mt = 0; mt < 4; ++mt) {
                float p0 = __expf(lgt[mt][0] - mx);
                float p1 = __expf(lgt[mt][1] - mx);
                float p2 = __expf(lgt[mt][2] - mx);
                float p3 = __expf(lgt[mt][3] - mx);
                sum += (p0 + p1) + (p2 + p3);
                pw[mt].x = pk2bf(p0, p1);
                pw[mt].y = pk2bf(p2, p3);
            }
            sum += __shfl_xor(sum, 16);
            sum += __shfl_xor(sum, 32);
            rs4[rt] = 1.f / sum;            // normalization deferred to PV epilogue
            #pragma unroll
            for (int mt = 0; mt < 4; ++mt)
                *(u32x2*)(pbuf + sw128(r, (mt * 16 + lg * 4) * 2)) = pw[mt];
        }
    }
    // NO barrier: P slice is wave-private (written and read by wave `wid` only)

    // ---- phase 4: PV swapped: outT[c][r] = vT · P -> natural store att[r][c]
    facc o2[2][4];
    {
        const char* pbuf = smem + wid * 8192;
        #pragma unroll
        for (int ct = 0; ct < 2; ++ct)
            #pragma unroll
            for (int rt = 0; rt < 4; ++rt) o2[ct][rt] = (facc){0, 0, 0, 0};
        #pragma unroll
        for (int ks = 0; ks < 2; ++ks) {
            bfrag av[2], pb[4];
            #pragma unroll
            for (int ct = 0; ct < 2; ++ct)
                av[ct] = *(const bfrag*)(vtbuf + sw128(wid * 32 + ct * 16 + l16, (ks * 32 + lg * 8) * 2));
            #pragma unroll
            for (int rt = 0; rt < 4; ++rt)
                pb[rt] = *(const bfrag*)(pbuf + sw128(rt * 16 + l16, (ks * 32 + lg * 8) * 2));
            #pragma unroll
            for (int ct = 0; ct < 2; ++ct)
                #pragma unroll
                for (int rt = 0; rt < 4; ++rt)
                    o2[ct][rt] = MFMA16(av[ct], pb[rt], o2[ct][rt]);
        }
    }
    __syncthreads();   // B3: all P/vT reads done -> att may overwrite qbuf
    {
        #pragma unroll
        for (int ct = 0; ct < 2; ++ct) {
            int c0 = wid * 32 + ct * 16 + lg * 4;
            #pragma unroll
            for (int rt = 0; rt < 4; ++rt) {
                int r = rt * 16 + l16;
                float sc = rs4[rt];
                u32x2 w;
                w.x = pk2bf(o2[ct][rt][0] * sc, o2[ct][rt][1] * sc);
                w.y = pk2bf(o2[ct][rt][2] * sc, o2[ct][rt][3] * sc);
                *(u32x2*)(qbuf + sw256(r, c0 * 2)) = w;
            }
        }
    }
    __syncthreads();   // B4: att stores -> proj reads

    // ---- phase 5: out proj, D[tok][o] = att · WpT, fp32 out
    {
        facc acco[8];
        #pragma unroll
        for (int nt = 0; nt < 8; ++nt) acco[nt] = (facc){0, 0, 0, 0};
        #pragma unroll
        for (int ks = 0; ks < 4; ++ks) {
            bfrag aa = *(const bfrag*)(qbuf + sw256(wid * 16 + l16, (ks * 32 + lg * 8) * 2));
            #pragma unroll
            for (int nt = 0; nt < 8; ++nt) {
                bfrag bw = *(const bfrag*)(wp + (nt * 16 + l16) * 128 + ks * 32 + lg * 8);
                acco[nt] = MFMA16(aa, bw, acco[nt]);
            }
        }
        float* ow = out + (size_t)win * (NTOK * DIM);
        #pragma unroll
        for (int nt = 0; nt < 8; ++nt) {
            int o = nt * 16 + l16;
            float b = bp[o];
            #pragma unroll
            for (int j = 0; j < 4; ++j) {
                int tok = wid * 16 + lg * 4 + j;
                if (tok < NTOK) ow[tok * 128 + o] = acco[nt][j] + b;
            }
        }
    }
}

extern "C" void kernel_launch(void* const* d_in, const int* in_sizes, int n_in,
                              void* d_out, int out_size, void* d_ws, size_t ws_size,
                              hipStream_t stream)
{
    const float* x    = (const float*)d_in[0];
    const float* mask = (const float*)d_in[1];
    const float* Wq   = (const float*)d_in[2];
    const float* bq   = (const float*)d_in[3];
    const float* Wk   = (const float*)d_in[4];
    const float* bk   = (const float*)d_in[5];
    const float* Wv   = (const float*)d_in[6];
    const float* bv   = (const float*)d_in[7];
    const float* Wp   = (const float*)d_in[8];
    const float* bp   = (const float*)d_in[9];
    const float* rlb  = (const float*)d_in[10];
    short* ws = (short*)d_ws;
    short* cmb = ws + 81920;
    const size_t need = ((size_t)81920 + (size_t)1024 * 4 * 64 * 64) * 2;
    const bool use_cmb = ws_size >= need;

    prep_w<<<64, 256, 0, stream>>>(Wq, Wk, Wv, Wp, rlb, ws);
    if (use_cmb) {
        prep_cmb<<<65536, 256, 0, stream>>>(mask, rlb, cmb);
        swin_fwd<true><<<16384, 256, 49152, stream>>>(x, mask, bq, bk, bv, bp,
            ws, ws + 16384, ws + 32768, ws + 49152, ws + 65536, cmb, (float*)d_out);
    } else {
        swin_fwd<false><<<16384, 256, 49152, stream>>>(x, mask, bq, bk, bv, bp,
            ws, ws + 16384, ws + 32768, ws + 49152, ws + 65536, cmb, (float*)d_out);
    }
}

// Round 3
// 541.286 us; speedup vs baseline: 2.0101x; 2.0101x over previous
//
#include <hip/hip_runtime.h>
#include <hip/hip_bf16.h>
#include <stdint.h>

#define NTOK 49
#define DIM 128
#define SCALE 0.17677669529663689f  /* 32^-0.5 */

typedef __attribute__((ext_vector_type(4))) float f32x4;
typedef __attribute__((ext_vector_type(2))) unsigned int u32x2;
typedef __attribute__((ext_vector_type(4))) unsigned int u32x4;
typedef __attribute__((ext_vector_type(8))) short bfrag;   // 8 bf16 = 4 VGPRs
typedef __attribute__((ext_vector_type(4))) short s16x4;   // 4 bf16 = 8B
typedef __attribute__((ext_vector_type(4))) float facc;    // 4 f32 accum

#define MFMA16(A,B,C) __builtin_amdgcn_mfma_f32_16x16x32_bf16(A,B,C,0,0,0)

__device__ __forceinline__ unsigned pk2bf(float a, float b) {  // RNE pack 2xbf16
    unsigned ua = __builtin_bit_cast(unsigned, a);
    unsigned ub = __builtin_bit_cast(unsigned, b);
    ua = ua + 0x7fffu + ((ua >> 16) & 1u);
    ub = ub + 0x7fffu + ((ub >> 16) & 1u);
    return (ua >> 16) | (ub & 0xffff0000u);
}
__device__ __forceinline__ short f2bf(float a) {
    unsigned ua = __builtin_bit_cast(unsigned, a);
    ua = ua + 0x7fffu + ((ua >> 16) & 1u);
    return (short)(ua >> 16);
}
__device__ __forceinline__ float bf2f(short s) {
    unsigned u = ((unsigned)(unsigned short)s) << 16;
    return __builtin_bit_cast(float, u);
}
// XOR swizzle (T2/G4): spread rows across 16B slots; 256B / 128B row strides
__device__ __forceinline__ int sw256(int row, int cb) { return row * 256 + (cb ^ ((row & 7) << 4)); }
__device__ __forceinline__ int sw128(int row, int cb) { return row * 128 + (cb ^ ((row & 7) << 4)); }

// ws (shorts): Wq_frag 0 | Wk_frag 16384 | Wv_frag 32768 | Wp_frag 49152 | RB_frag 65536
// Fragment order: wf[((tile*4+ks)*64 + lane)*8 + e] = W[row*128+col],
//   row = tile*16 + (lane&15), col = ks*32 + (lane>>4)*8 + e
// -> in-kernel fragment load = ONE contiguous 1KB wave transaction.
__global__ void prep_w(const float* __restrict__ Wq, const float* __restrict__ Wk,
                       const float* __restrict__ Wv, const float* __restrict__ Wp,
                       const float* __restrict__ relb, short* __restrict__ ws)
{
    int t = blockIdx.x * 256 + threadIdx.x;
    if (t >= 16384) return;
    int e = t & 7, lane = (t >> 3) & 63, ks = (t >> 9) & 3, tile = t >> 11;
    int row = tile * 16 + (lane & 15);
    int col = ks * 32 + (lane >> 4) * 8 + e;
    int src = row * 128 + col;
    ws[t]         = f2bf(Wq[src]);
    ws[16384 + t] = f2bf(Wk[src]);
    ws[32768 + t] = f2bf(Wv[src]);
    ws[49152 + t] = f2bf(Wp[src]);
    // rel-bias fragment table: rbf[((h*16 + rt*4 + mt)*64 + lane)*4 + e2]
    int e2 = t & 3, lane2 = (t >> 2) & 63, mt = (t >> 8) & 3, rt = (t >> 10) & 3, h = t >> 12;
    int r = rt * 16 + (lane2 & 15);
    int m = mt * 16 + (lane2 >> 4) * 4 + e2;
    float v = 0.f;
    if (r < NTOK && m < NTOK) {
        int idx = ((r / 7 - m / 7) + 6) * 13 + ((r % 7) - (m % 7) + 6);
        v = relb[idx * 4 + h];
    }
    ws[65536 + t] = f2bf(v);
}

// One block per window; 4 waves; wave = head (o-strip wid*32..+32) everywhere.
// LDS 64KB: q[64][256B] @0 | k @16K | vT[128][128B] @32K | x->mask->att @48K
// P[4][8KB] (wave-private) overlays q∪k after B2.
__global__ __launch_bounds__(256, 2) void swin_fwd(
    const float* __restrict__ x, const float* __restrict__ mask,
    const float* __restrict__ bq, const float* __restrict__ bk,
    const float* __restrict__ bv, const float* __restrict__ bp,
    const short* __restrict__ wqf, const short* __restrict__ wkf,
    const short* __restrict__ wvf, const short* __restrict__ wpf,
    const short* __restrict__ rbf, float* __restrict__ out)
{
    extern __shared__ char smem[];
    char* qbuf  = smem;
    char* kbuf  = smem + 16384;
    char* vtbuf = smem + 32768;
    char* r4    = smem + 49152;

    const int win = blockIdx.x;
    const int tid = threadIdx.x;
    const int wid = tid >> 6;
    const int lane = tid & 63;
    const int l16 = lane & 15;
    const int lg = lane >> 4;

    // ---- P0: stage x -> r4 bf16 [64][256B] swizzled (coalesced f32x4 reads)
    {
        const float* xw = x + (size_t)win * (NTOK * DIM);
        #pragma unroll
        for (int i = 0; i < 7; ++i) {
            int i4 = i * 256 + tid;
            if (i4 < 1568) {
                f32x4 f = *(const f32x4*)(xw + i4 * 4);
                int tok = i4 >> 5, col = (i4 & 31) * 4;
                u32x2 w; w.x = pk2bf(f.x, f.y); w.y = pk2bf(f.z, f.w);
                *(u32x2*)(r4 + sw256(tok, col * 2)) = w;
            }
        }
        if (tid < 240) {   // zero pad rows 49..63
            u32x4 z = {0, 0, 0, 0};
            *(u32x4*)(r4 + 49 * 256 + tid * 16) = z;
        }
    }
    // hoist weight-fragment loads (contiguous 1KB each) to overlap x staging
    bfrag aq[2][4], ak[2][4], av[2][4];
    float bqv[2][4], bkv[2][4], bvv[2][4];
    #pragma unroll
    for (int mt = 0; mt < 2; ++mt) {
        #pragma unroll
        for (int ks = 0; ks < 4; ++ks) {
            int fi = (((wid * 2 + mt) * 4 + ks) * 64 + lane) * 8;
            aq[mt][ks] = *(const bfrag*)(wqf + fi);
            ak[mt][ks] = *(const bfrag*)(wkf + fi);
            av[mt][ks] = *(const bfrag*)(wvf + fi);
        }
        #pragma unroll
        for (int j = 0; j < 4; ++j) {
            int o = wid * 32 + mt * 16 + lg * 4 + j;
            bqv[mt][j] = bq[o]; bkv[mt][j] = bk[o]; bvv[mt][j] = bv[o];
        }
    }
    __syncthreads();   // B0: x staged

    // ---- P1: QKV. A = weight strip (wave's head dims), B = x tiles from LDS.
    //      q,k natural store -> row-major [tok][o]; v transpose-store -> vT[o][tok].
    {
        #pragma unroll
        for (int nt = 0; nt < 4; ++nt) {
            bfrag bx[4];
            #pragma unroll
            for (int ks = 0; ks < 4; ++ks)
                bx[ks] = *(const bfrag*)(r4 + sw256(nt * 16 + l16, (ks * 32 + lg * 8) * 2));
            facc accq[2] = {{0,0,0,0},{0,0,0,0}};
            facc acck[2] = {{0,0,0,0},{0,0,0,0}};
            facc accv[2] = {{0,0,0,0},{0,0,0,0}};
            #pragma unroll
            for (int ks = 0; ks < 4; ++ks)
                #pragma unroll
                for (int mt = 0; mt < 2; ++mt) {
                    accq[mt] = MFMA16(aq[mt][ks], bx[ks], accq[mt]);
                    acck[mt] = MFMA16(ak[mt][ks], bx[ks], acck[mt]);
                    accv[mt] = MFMA16(av[mt][ks], bx[ks], accv[mt]);
                }
            int tok = nt * 16 + l16;
            #pragma unroll
            for (int mt = 0; mt < 2; ++mt) {
                int o0 = wid * 32 + mt * 16 + lg * 4;
                u32x2 wq2, wk2;
                wq2.x = pk2bf((accq[mt][0] + bqv[mt][0]) * SCALE, (accq[mt][1] + bqv[mt][1]) * SCALE);
                wq2.y = pk2bf((accq[mt][2] + bqv[mt][2]) * SCALE, (accq[mt][3] + bqv[mt][3]) * SCALE);
                wk2.x = pk2bf(acck[mt][0] + bkv[mt][0], acck[mt][1] + bkv[mt][1]);
                wk2.y = pk2bf(acck[mt][2] + bkv[mt][2], acck[mt][3] + bkv[mt][3]);
                *(u32x2*)(qbuf + sw256(tok, o0 * 2)) = wq2;
                *(u32x2*)(kbuf + sw256(tok, o0 * 2)) = wk2;
                #pragma unroll
                for (int j = 0; j < 4; ++j)   // transpose store, 2-way free (swizzled)
                    *(short*)(vtbuf + sw128(o0 + j, tok * 2)) = f2bf(accv[mt][j] + bvv[mt][j]);
            }
        }
    }
    __syncthreads();   // B1: QKV stores done; x dead

    // ---- P2: stage mask -> r4 as [64][64] f32 swizzled (pads = -1e30) + QK^T
    {
        const float* mw = mask + (size_t)(win & 1023) * (NTOK * NTOK);
        #pragma unroll
        for (int i = 0; i < 16; ++i) {
            int flat = i * 256 + tid;
            int r = flat >> 6, m = flat & 63;
            float v = -1e30f;
            if (r < NTOK && m < NTOK) v = mw[r * 49 + m];
            *(float*)(r4 + sw256(r, m * 4)) = v;
        }
    }
    facc s[4][4];   // s[mt][rt]: S^T[m][r], head = wid
    {
        bfrag ka[4], qb[4];
        int cb = (wid * 32 + lg * 8) * 2;
        #pragma unroll
        for (int t = 0; t < 4; ++t) {
            ka[t] = *(const bfrag*)(kbuf + sw256(t * 16 + l16, cb));
            qb[t] = *(const bfrag*)(qbuf + sw256(t * 16 + l16, cb));
        }
        #pragma unroll
        for (int mt = 0; mt < 4; ++mt)
            #pragma unroll
            for (int rt = 0; rt < 4; ++rt) {
                facc z = {0, 0, 0, 0};
                s[mt][rt] = MFMA16(ka[mt], qb[rt], z);
            }
    }
    __syncthreads();   // B2: q/k reads + mask writes done -> P may overwrite q∪k

    // ---- P3: softmax over key m; bias = rbf frag (coalesced) + mask LDS frag
    float rs4[4];
    {
        char* pbuf = smem + wid * 8192;
        #pragma unroll
        for (int rt = 0; rt < 4; ++rt) {
            int r = rt * 16 + l16;
            float lgt[4][4];
            float mx = -3e38f;
            #pragma unroll
            for (int mt = 0; mt < 4; ++mt) {
                s16x4 b4 = *(const s16x4*)(rbf + (((wid * 16 + rt * 4 + mt) * 64 + lane) * 4));
                f32x4 mk = *(const f32x4*)(r4 + sw256(r, (mt * 16 + lg * 4) * 4));
                #pragma unroll
                for (int j = 0; j < 4; ++j) {
                    float v = s[mt][rt][j] + bf2f(b4[j]) + mk[j];
                    lgt[mt][j] = v;
                    mx = fmaxf(mx, v);
                }
            }
            mx = fmaxf(mx, __shfl_xor(mx, 16));
            mx = fmaxf(mx, __shfl_xor(mx, 32));
            float sum = 0.f;
            u32x2 pw[4];
            #pragma unroll
            for (int mt = 0; mt < 4; ++mt) {
                float p0 = __expf(lgt[mt][0] - mx);
                float p1 = __expf(lgt[mt][1] - mx);
                float p2 = __expf(lgt[mt][2] - mx);
                float p3 = __expf(lgt[mt][3] - mx);
                sum += (p0 + p1) + (p2 + p3);
                pw[mt].x = pk2bf(p0, p1);
                pw[mt].y = pk2bf(p2, p3);
            }
            sum += __shfl_xor(sum, 16);
            sum += __shfl_xor(sum, 32);
            rs4[rt] = 1.f / sum;            // normalization deferred to PV epilogue
            #pragma unroll
            for (int mt = 0; mt < 4; ++mt)
                *(u32x2*)(pbuf + sw128(r, (mt * 16 + lg * 4) * 2)) = pw[mt];
        }
    }
    // NO barrier: P slice and vT rows [wid*32, wid*32+32) are wave-private

    // ---- P4: PV swapped: outT[c][r] = vT · P -> natural store att[r][c]
    facc o2[2][4];
    {
        const char* pbuf = smem + wid * 8192;
        #pragma unroll
        for (int ct = 0; ct < 2; ++ct)
            #pragma unroll
            for (int rt = 0; rt < 4; ++rt) o2[ct][rt] = (facc){0, 0, 0, 0};
        #pragma unroll
        for (int ks = 0; ks < 2; ++ks) {
            bfrag avf[2], pb[4];
            #pragma unroll
            for (int ct = 0; ct < 2; ++ct)
                avf[ct] = *(const bfrag*)(vtbuf + sw128(wid * 32 + ct * 16 + l16, (ks * 32 + lg * 8) * 2));
            #pragma unroll
            for (int rt = 0; rt < 4; ++rt)
                pb[rt] = *(const bfrag*)(pbuf + sw128(rt * 16 + l16, (ks * 32 + lg * 8) * 2));
            #pragma unroll
            for (int ct = 0; ct < 2; ++ct)
                #pragma unroll
                for (int rt = 0; rt < 4; ++rt)
                    o2[ct][rt] = MFMA16(avf[ct], pb[rt], o2[ct][rt]);
        }
    }
    __syncthreads();   // B3: mask reads done -> att may overwrite r4
    {
        #pragma unroll
        for (int ct = 0; ct < 2; ++ct) {
            int c0 = wid * 32 + ct * 16 + lg * 4;
            #pragma unroll
            for (int rt = 0; rt < 4; ++rt) {
                int r = rt * 16 + l16;
                float sc = rs4[rt];
                u32x2 w;
                w.x = pk2bf(o2[ct][rt][0] * sc, o2[ct][rt][1] * sc);
                w.y = pk2bf(o2[ct][rt][2] * sc, o2[ct][rt][3] * sc);
                *(u32x2*)(r4 + sw256(r, c0 * 2)) = w;
            }
        }
    }
    __syncthreads();   // B4: att stores -> proj reads

    // ---- P5: out proj. A = wp strip, B = att tiles -> D[o][tok],
    //      natural epilogue = contiguous f32x4 global stores.
    {
        bfrag ap[2][4];
        float bpv[2][4];
        #pragma unroll
        for (int mt = 0; mt < 2; ++mt) {
            #pragma unroll
            for (int ks = 0; ks < 4; ++ks)
                ap[mt][ks] = *(const bfrag*)(wpf + (((wid * 2 + mt) * 4 + ks) * 64 + lane) * 8);
            #pragma unroll
            for (int j = 0; j < 4; ++j)
                bpv[mt][j] = bp[wid * 32 + mt * 16 + lg * 4 + j];
        }
        facc acco[2][4];
        #pragma unroll
        for (int mt = 0; mt < 2; ++mt)
            #pragma unroll
            for (int tt = 0; tt < 4; ++tt) acco[mt][tt] = (facc){0, 0, 0, 0};
        #pragma unroll
        for (int tt = 0; tt < 4; ++tt) {
            bfrag ba[4];
            #pragma unroll
            for (int ks = 0; ks < 4; ++ks)
                ba[ks] = *(const bfrag*)(r4 + sw256(tt * 16 + l16, (ks * 32 + lg * 8) * 2));
            #pragma unroll
            for (int ks = 0; ks < 4; ++ks)
                #pragma unroll
                for (int mt = 0; mt < 2; ++mt)
                    acco[mt][tt] = MFMA16(ap[mt][ks], ba[ks], acco[mt][tt]);
        }
        float* ow = out + (size_t)win * (NTOK * DIM);
        #pragma unroll
        for (int tt = 0; tt < 4; ++tt) {
            int tok = tt * 16 + l16;
            if (tok < NTOK) {
                #pragma unroll
                for (int mt = 0; mt < 2; ++mt) {
                    int o0 = wid * 32 + mt * 16 + lg * 4;
                    f32x4 w;
                    w.x = acco[mt][tt][0] + bpv[mt][0];
                    w.y = acco[mt][tt][1] + bpv[mt][1];
                    w.z = acco[mt][tt][2] + bpv[mt][2];
                    w.w = acco[mt][tt][3] + bpv[mt][3];
                    *(f32x4*)(ow + tok * 128 + o0) = w;
                }
            }
        }
    }
}

extern "C" void kernel_launch(void* const* d_in, const int* in_sizes, int n_in,
                              void* d_out, int out_size, void* d_ws, size_t ws_size,
                              hipStream_t stream)
{
    const float* x    = (const float*)d_in[0];
    const float* mask = (const float*)d_in[1];
    const float* Wq   = (const float*)d_in[2];
    const float* bq   = (const float*)d_in[3];
    const float* Wk   = (const float*)d_in[4];
    const float* bk   = (const float*)d_in[5];
    const float* Wv   = (const float*)d_in[6];
    const float* bv   = (const float*)d_in[7];
    const float* Wp   = (const float*)d_in[8];
    const float* bp   = (const float*)d_in[9];
    const float* rlb  = (const float*)d_in[10];
    short* ws = (short*)d_ws;

    prep_w<<<64, 256, 0, stream>>>(Wq, Wk, Wv, Wp, rlb, ws);
    swin_fwd<<<16384, 256, 65536, stream>>>(x, mask, bq, bk, bv, bp,
        ws, ws + 16384, ws + 32768, ws + 49152, ws + 65536, (float*)d_out);
}

// Round 6
// 406.233 us; speedup vs baseline: 2.6784x; 1.3325x over previous
//
#include <hip/hip_runtime.h>
#include <hip/hip_bf16.h>
#include <stdint.h>

#define NTOK 49
#define LOG2E 1.4426950408889634f
#define SCALE2 0.25507662683243807f   /* 32^-0.5 * log2(e) */

typedef __attribute__((ext_vector_type(4))) float f32x4;
typedef __attribute__((ext_vector_type(2))) unsigned int u32x2;
typedef __attribute__((ext_vector_type(4))) unsigned int u32x4;
typedef __attribute__((ext_vector_type(8))) short bfrag;   // 8 bf16 = 4 VGPRs
typedef __attribute__((ext_vector_type(4))) short s16x4;   // 4 bf16 = 8B
typedef __attribute__((ext_vector_type(4))) float facc;    // 4 f32 accum

#define MFMA16(A,B,C) __builtin_amdgcn_mfma_f32_16x16x32_bf16(A,B,C,0,0,0)
#define EXP2(x) __builtin_amdgcn_exp2f(x)

// HW bf16 pack — T12 recipe: no builtin on gfx950, inline asm v_cvt_pk_bf16_f32
__device__ __forceinline__ unsigned pk2bf(float a, float b) {
    unsigned r;
    asm("v_cvt_pk_bf16_f32 %0, %1, %2" : "=v"(r) : "v"(a), "v"(b));
    return r;
}
__device__ __forceinline__ short f2bf(float a) {   // prep-only, manual RNE
    unsigned ua = __builtin_bit_cast(unsigned, a);
    ua = ua + 0x7fffu + ((ua >> 16) & 1u);
    return (short)(ua >> 16);
}
__device__ __forceinline__ float bf2f(short s) {
    unsigned u = ((unsigned)(unsigned short)s) << 16;
    return __builtin_bit_cast(float, u);
}
// XOR swizzle (T2/G4)
__device__ __forceinline__ int sw256(int row, int cb) { return row * 256 + (cb ^ ((row & 7) << 4)); }
__device__ __forceinline__ int sw128(int row, int cb) { return row * 128 + (cb ^ ((row & 7) << 4)); }

// ws (shorts): Wq_frag 0 | Wk_frag 16384 | Wv_frag 32768 | Wp_frag 49152 |
//              RB_frag (×log2e) 65536 | cmb_frag 81920 (if ws_size permits)
__global__ void prep_w(const float* __restrict__ Wq, const float* __restrict__ Wk,
                       const float* __restrict__ Wv, const float* __restrict__ Wp,
                       const float* __restrict__ relb, short* __restrict__ ws)
{
    int t = blockIdx.x * 256 + threadIdx.x;
    if (t >= 16384) return;
    int e = t & 7, lane = (t >> 3) & 63, ks = (t >> 9) & 3, tile = t >> 11;
    int row = tile * 16 + (lane & 15);
    int col = ks * 32 + (lane >> 4) * 8 + e;
    int src = row * 128 + col;
    ws[t]         = f2bf(Wq[src]);
    ws[16384 + t] = f2bf(Wk[src]);
    ws[32768 + t] = f2bf(Wv[src]);
    ws[49152 + t] = f2bf(Wp[src]);
    // rel-bias fragment table (×log2e): rbf[((h*16 + rt*4 + mt)*64 + lane)*4 + e2]
    int e2 = t & 3, lane2 = (t >> 2) & 63, mt = (t >> 8) & 3, rt = (t >> 10) & 3, h = t >> 12;
    int r = rt * 16 + (lane2 & 15);
    int m = mt * 16 + (lane2 >> 4) * 4 + e2;
    float v = 0.f;
    if (r < NTOK && m < NTOK) {
        int idx = ((r / 7 - m / 7) + 6) * 13 + ((r % 7) - (m % 7) + 6);
        v = relb[idx * 4 + h] * LOG2E;
    }
    ws[65536 + t] = f2bf(v);
}

// cmb_frag[w][h][rt][mt][lane][4] = (mask + rel_bias)*log2e, pads = -1e30 (bf16)
__global__ void prep_cmb(const float* __restrict__ mask, const float* __restrict__ relb,
                         short* __restrict__ cmb)
{
    int t = blockIdx.x * 256 + threadIdx.x;            // 16,777,216 entries
    int e = t & 3, lane = (t >> 2) & 63, mt = (t >> 8) & 3, rt = (t >> 10) & 3;
    int h = (t >> 12) & 3, w = t >> 14;
    int r = rt * 16 + (lane & 15);
    int m = mt * 16 + (lane >> 4) * 4 + e;
    float v = -1e30f;
    if (r < NTOK && m < NTOK) {
        int idx = ((r / 7 - m / 7) + 6) * 13 + ((r % 7) - (m % 7) + 6);
        v = (mask[w * (NTOK * NTOK) + r * NTOK + m] + relb[idx * 4 + h]) * LOG2E;
    }
    cmb[t] = f2bf(v);
}

// P placement inside q∪k after QK^T (barrier-protected; the XOR crosses 64B
// strips so this is NOT wave-private — bijective per row, so no collisions).
__device__ __forceinline__ char* pstrip(char* smem_, int wid, int r, int mb) {
    return smem_ + ((mb >> 6) << 14) + r * 256 + ((wid * 64 + (mb & 63)) ^ ((r & 7) << 4));
}

// One block per window; 4 waves; wave = head (o-strip wid*32..+32) everywhere.
// LDS 64KB: q[64][256B] @0 | k @16K | vT[128][128B] @32K | x -> att @48K
// Barriers: B0 (x staged), B_P (QK^T reads done -> P may overwrite q∪k),
//           B1 (x dead -> att into r4), B2 (att staged).
template<bool CMBF>
__global__ __launch_bounds__(256, 2) void swin_fwd(
    const float* __restrict__ x, const float* __restrict__ mask,
    const float* __restrict__ bq, const float* __restrict__ bk,
    const float* __restrict__ bv, const float* __restrict__ bp,
    const short* __restrict__ wqf, const short* __restrict__ wkf,
    const short* __restrict__ wvf, const short* __restrict__ wpf,
    const short* __restrict__ rbf, const short* __restrict__ cmbf,
    float* __restrict__ out)
{
    extern __shared__ char smem[];
    char* qbuf  = smem;
    char* kbuf  = smem + 16384;
    char* vtbuf = smem + 32768;
    char* r4    = smem + 49152;

    const int win = blockIdx.x;
    const int tid = threadIdx.x;
    const int wid = tid >> 6;
    const int lane = tid & 63;
    const int l16 = lane & 15;
    const int lg = lane >> 4;

    // ---- P0: stage x -> r4 bf16 [64][256B] swizzled (coalesced f32x4 reads)
    {
        const float* xw = x + (size_t)win * (NTOK * 128);
        #pragma unroll
        for (int i = 0; i < 7; ++i) {
            int i4 = i * 256 + tid;
            if (i4 < 1568) {
                f32x4 f = *(const f32x4*)(xw + i4 * 4);
                int tok = i4 >> 5, col = (i4 & 31) * 4;
                u32x2 w; w.x = pk2bf(f.x, f.y); w.y = pk2bf(f.z, f.w);
                *(u32x2*)(r4 + sw256(tok, col * 2)) = w;
            }
        }
        if (tid < 240) {   // zero pad rows 49..63
            u32x4 z = {0, 0, 0, 0};
            *(u32x4*)(r4 + 49 * 256 + tid * 16) = z;
        }
    }
    // hoist weight-fragment loads (contiguous 1KB each) to overlap x staging
    bfrag aq[2][4], ak[2][4], av[2][4];
    float bqv[2][4], bkv[2][4], bvv2[2];
    #pragma unroll
    for (int mt = 0; mt < 2; ++mt) {
        #pragma unroll
        for (int ks = 0; ks < 4; ++ks) {
            int fi = (((wid * 2 + mt) * 4 + ks) * 64 + lane) * 8;
            aq[mt][ks] = *(const bfrag*)(wqf + fi);
            ak[mt][ks] = *(const bfrag*)(wkf + fi);
            av[mt][ks] = *(const bfrag*)(wvf + fi);
        }
        #pragma unroll
        for (int j = 0; j < 4; ++j) {
            int o = wid * 32 + mt * 16 + lg * 4 + j;
            bqv[mt][j] = bq[o]; bkv[mt][j] = bk[o];
        }
        bvv2[mt] = bv[wid * 32 + mt * 16 + l16];
    }
    __syncthreads();   // B0: x staged

    // ---- P1: QKV. q,k: A=weight strip, B=x -> D[o][tok] -> row-major q,k strips.
    //      v: A=x, B=wv frag -> D[tok][o] -> vT rows, packed 8B stores.
    {
        #pragma unroll
        for (int nt = 0; nt < 4; ++nt) {
            bfrag bx[4];
            #pragma unroll
            for (int ks = 0; ks < 4; ++ks)
                bx[ks] = *(const bfrag*)(r4 + sw256(nt * 16 + l16, (ks * 32 + lg * 8) * 2));
            facc accq[2] = {{0,0,0,0},{0,0,0,0}};
            facc acck[2] = {{0,0,0,0},{0,0,0,0}};
            facc accv[2] = {{0,0,0,0},{0,0,0,0}};
            #pragma unroll
            for (int ks = 0; ks < 4; ++ks)
                #pragma unroll
                for (int mt = 0; mt < 2; ++mt) {
                    accq[mt] = MFMA16(aq[mt][ks], bx[ks], accq[mt]);
                    acck[mt] = MFMA16(ak[mt][ks], bx[ks], acck[mt]);
                    accv[mt] = MFMA16(bx[ks], av[mt][ks], accv[mt]);
                }
            int tok = nt * 16 + l16;
            #pragma unroll
            for (int mt = 0; mt < 2; ++mt) {
                int o0 = wid * 32 + mt * 16 + lg * 4;
                u32x2 wq2, wk2, wv2;
                wq2.x = pk2bf((accq[mt][0] + bqv[mt][0]) * SCALE2, (accq[mt][1] + bqv[mt][1]) * SCALE2);
                wq2.y = pk2bf((accq[mt][2] + bqv[mt][2]) * SCALE2, (accq[mt][3] + bqv[mt][3]) * SCALE2);
                wk2.x = pk2bf(acck[mt][0] + bkv[mt][0], acck[mt][1] + bkv[mt][1]);
                wk2.y = pk2bf(acck[mt][2] + bkv[mt][2], acck[mt][3] + bkv[mt][3]);
                *(u32x2*)(qbuf + sw256(tok, o0 * 2)) = wq2;
                *(u32x2*)(kbuf + sw256(tok, o0 * 2)) = wk2;
                // v: lane holds tok' = nt*16+lg*4+j, o' = wid*32+mt*16+l16
                wv2.x = pk2bf(accv[mt][0] + bvv2[mt], accv[mt][1] + bvv2[mt]);
                wv2.y = pk2bf(accv[mt][2] + bvv2[mt], accv[mt][3] + bvv2[mt]);
                *(u32x2*)(vtbuf + sw128(wid * 32 + mt * 16 + l16, (nt * 16 + lg * 4) * 2)) = wv2;
            }
        }
    }
    // NO barrier: each wave reads back exactly the bytes it wrote (bijective swizzle)

    // ---- P2: QK^T (S^T = k·qT) from own strips
    facc s[4][4];   // s[mt][rt]: S^T[m][r], head = wid
    {
        bfrag ka[4], qb[4];
        int cb = (wid * 32 + lg * 8) * 2;
        #pragma unroll
        for (int t = 0; t < 4; ++t) {
            ka[t] = *(const bfrag*)(kbuf + sw256(t * 16 + l16, cb));
            qb[t] = *(const bfrag*)(qbuf + sw256(t * 16 + l16, cb));
        }
        #pragma unroll
        for (int mt = 0; mt < 4; ++mt)
            #pragma unroll
            for (int rt = 0; rt < 4; ++rt) {
                facc z = {0, 0, 0, 0};
                s[mt][rt] = MFMA16(ka[mt], qb[rt], z);
            }
    }

    // hoist combined-bias loads (coalesced 512B/instr) BEFORE the P-barrier so
    // their global latency hides under the barrier wait
    s16x4 b4r[4][4];
    if (CMBF) {
        const short* cw = cmbf + ((size_t)(win & 1023) * 4 + wid) * 4096;
        #pragma unroll
        for (int rt = 0; rt < 4; ++rt)
            #pragma unroll
            for (int mt = 0; mt < 4; ++mt)
                b4r[rt][mt] = *(const s16x4*)(cw + (rt * 4 + mt) * 256 + lane * 4);
    }

    if (CMBF) {
        __syncthreads();   // B_P: all QK^T reads of q∪k done -> P may overwrite
    } else {
        // fallback: stage mask (needs x dead everywhere -> 2 barriers)
        __syncthreads();   // Bf1: all waves past P2 -> x dead, q∪k reads done
        const float* mw = mask + (size_t)(win & 1023) * (NTOK * NTOK);
        #pragma unroll
        for (int i = 0; i < 16; ++i) {
            int flat = i * 256 + tid;
            int r = flat >> 6, m = flat & 63;
            float v = -1e30f;
            if (r < NTOK && m < NTOK) v = mw[r * 49 + m] * LOG2E;
            *(float*)(r4 + sw256(r, m * 4)) = v;
        }
        __syncthreads();   // Bf2: mask staged
    }

    // ---- P3: softmax over key m (log2 domain); P -> q∪k (barrier-protected)
    float rs4[4];
    {
        #pragma unroll
        for (int rt = 0; rt < 4; ++rt) {
            int r = rt * 16 + l16;
            float lgt[4][4];
            float mx = -3e38f;
            #pragma unroll
            for (int mt = 0; mt < 4; ++mt) {
                if (CMBF) {
                    #pragma unroll
                    for (int j = 0; j < 4; ++j) {
                        float v = s[mt][rt][j] + bf2f(b4r[rt][mt][j]);
                        lgt[mt][j] = v;
                        mx = fmaxf(mx, v);
                    }
                } else {
                    s16x4 b4 = *(const s16x4*)(rbf + ((wid * 16 + rt * 4 + mt) * 64 + lane) * 4);
                    f32x4 mk = *(const f32x4*)(r4 + sw256(r, (mt * 16 + lg * 4) * 4));
                    #pragma unroll
                    for (int j = 0; j < 4; ++j) {
                        float v = s[mt][rt][j] + bf2f(b4[j]) + mk[j];
                        lgt[mt][j] = v;
                        mx = fmaxf(mx, v);
                    }
                }
            }
            mx = fmaxf(mx, __shfl_xor(mx, 16));
            mx = fmaxf(mx, __shfl_xor(mx, 32));
            float sum = 0.f;
            u32x2 pw[4];
            #pragma unroll
            for (int mt = 0; mt < 4; ++mt) {
                float p0 = EXP2(lgt[mt][0] - mx);
                float p1 = EXP2(lgt[mt][1] - mx);
                float p2 = EXP2(lgt[mt][2] - mx);
                float p3 = EXP2(lgt[mt][3] - mx);
                sum += (p0 + p1) + (p2 + p3);
                pw[mt].x = pk2bf(p0, p1);
                pw[mt].y = pk2bf(p2, p3);
            }
            sum += __shfl_xor(sum, 16);
            sum += __shfl_xor(sum, 32);
            rs4[rt] = __builtin_amdgcn_rcpf(sum);   // deferred normalization
            #pragma unroll
            for (int mt = 0; mt < 4; ++mt)
                *(u32x2*)pstrip(smem, wid, r, mt * 32 + lg * 8) = pw[mt];
        }
    }
    // NO barrier: P read back by the same wave that wrote it (same addresses)

    // ---- P4: PV swapped: outT[c][r] = vT · P (vT rows are wave-private)
    facc o2[2][4];
    {
        #pragma unroll
        for (int ct = 0; ct < 2; ++ct)
            #pragma unroll
            for (int rt = 0; rt < 4; ++rt) o2[ct][rt] = (facc){0, 0, 0, 0};
        #pragma unroll
        for (int ks = 0; ks < 2; ++ks) {
            bfrag avf[2], pb[4];
            #pragma unroll
            for (int ct = 0; ct < 2; ++ct)
                avf[ct] = *(const bfrag*)(vtbuf + sw128(wid * 32 + ct * 16 + l16, (ks * 32 + lg * 8) * 2));
            #pragma unroll
            for (int rt = 0; rt < 4; ++rt)
                pb[rt] = *(const bfrag*)pstrip(smem, wid, rt * 16 + l16, ks * 64 + lg * 16);
            #pragma unroll
            for (int ct = 0; ct < 2; ++ct)
                #pragma unroll
                for (int rt = 0; rt < 4; ++rt)
                    o2[ct][rt] = MFMA16(avf[ct], pb[rt], o2[ct][rt]);
        }
    }
    // hoist proj weight frags before the barrier (independent global loads)
    bfrag ap[2][4];
    float bpv[2][4];
    #pragma unroll
    for (int mt = 0; mt < 2; ++mt) {
        #pragma unroll
        for (int ks = 0; ks < 4; ++ks)
            ap[mt][ks] = *(const bfrag*)(wpf + (((wid * 2 + mt) * 4 + ks) * 64 + lane) * 8);
        #pragma unroll
        for (int j = 0; j < 4; ++j)
            bpv[mt][j] = bp[wid * 32 + mt * 16 + lg * 4 + j];
    }
    __syncthreads();   // B1: x (or mask) reads done everywhere -> att into r4
    {
        #pragma unroll
        for (int ct = 0; ct < 2; ++ct) {
            int c0 = wid * 32 + ct * 16 + lg * 4;
            #pragma unroll
            for (int rt = 0; rt < 4; ++rt) {
                int r = rt * 16 + l16;
                float sc = rs4[rt];
                u32x2 w;
                w.x = pk2bf(o2[ct][rt][0] * sc, o2[ct][rt][1] * sc);
                w.y = pk2bf(o2[ct][rt][2] * sc, o2[ct][rt][3] * sc);
                *(u32x2*)(r4 + sw256(r, c0 * 2)) = w;
            }
        }
    }
    __syncthreads();   // B2: att staged -> proj reads

    // ---- P5: out proj. A = wp strip, B = att tiles -> D[o][tok];
    //      epilogue = contiguous f32x4 global stores.
    {
        facc acco[2][4];
        #pragma unroll
        for (int mt = 0; mt < 2; ++mt)
            #pragma unroll
            for (int tt = 0; tt < 4; ++tt) acco[mt][tt] = (facc){0, 0, 0, 0};
        #pragma unroll
        for (int tt = 0; tt < 4; ++tt) {
            bfrag ba[4];
            #pragma unroll
            for (int ks = 0; ks < 4; ++ks)
                ba[ks] = *(const bfrag*)(r4 + sw256(tt * 16 + l16, (ks * 32 + lg * 8) * 2));
            #pragma unroll
            for (int ks = 0; ks < 4; ++ks)
                #pragma unroll
                for (int mt = 0; mt < 2; ++mt)
                    acco[mt][tt] = MFMA16(ap[mt][ks], ba[ks], acco[mt][tt]);
        }
        float* ow = out + (size_t)win * (NTOK * 128);
        #pragma unroll
        for (int tt = 0; tt < 4; ++tt) {
            int tok = tt * 16 + l16;
            if (tok < NTOK) {
                #pragma unroll
                for (int mt = 0; mt < 2; ++mt) {
                    int o0 = wid * 32 + mt * 16 + lg * 4;
                    f32x4 w;
                    w.x = acco[mt][tt][0] + bpv[mt][0];
                    w.y = acco[mt][tt][1] + bpv[mt][1];
                    w.z = acco[mt][tt][2] + bpv[mt][2];
                    w.w = acco[mt][tt][3] + bpv[mt][3];
                    *(f32x4*)(ow + tok * 128 + o0) = w;
                }
            }
        }
    }
}

extern "C" void kernel_launch(void* const* d_in, const int* in_sizes, int n_in,
                              void* d_out, int out_size, void* d_ws, size_t ws_size,
                              hipStream_t stream)
{
    const float* x    = (const float*)d_in[0];
    const float* mask = (const float*)d_in[1];
    const float* Wq   = (const float*)d_in[2];
    const float* bq   = (const float*)d_in[3];
    const float* Wk   = (const float*)d_in[4];
    const float* bk   = (const float*)d_in[5];
    const float* Wv   = (const float*)d_in[6];
    const float* bv   = (const float*)d_in[7];
    const float* Wp   = (const float*)d_in[8];
    const float* bp   = (const float*)d_in[9];
    const float* rlb  = (const float*)d_in[10];
    short* ws = (short*)d_ws;
    short* cmb = ws + 81920;
    const size_t need = ((size_t)81920 + (size_t)16777216) * 2;
    const bool use_cmb = ws_size >= need;

    prep_w<<<64, 256, 0, stream>>>(Wq, Wk, Wv, Wp, rlb, ws);
    if (use_cmb) {
        prep_cmb<<<65536, 256, 0, stream>>>(mask, rlb, cmb);
        swin_fwd<true><<<16384, 256, 65536, stream>>>(x, mask, bq, bk, bv, bp,
            ws, ws + 16384, ws + 32768, ws + 49152, ws + 65536, cmb, (float*)d_out);
    } else {
        swin_fwd<false><<<16384, 256, 65536, stream>>>(x, mask, bq, bk, bv, bp,
            ws, ws + 16384, ws + 32768, ws + 49152, ws + 65536, cmb, (float*)d_out);
    }
}

// Round 7
// 370.587 us; speedup vs baseline: 2.9360x; 1.0962x over previous
//
#include <hip/hip_runtime.h>
#include <hip/hip_bf16.h>
#include <stdint.h>

#define NTOK 49
#define LOG2E 1.4426950408889634f
#define SCALE2 0.25507662683243807f   /* 32^-0.5 * log2(e) */

typedef __attribute__((ext_vector_type(4))) float f32x4;
typedef __attribute__((ext_vector_type(2))) unsigned int u32x2;
typedef __attribute__((ext_vector_type(4))) unsigned int u32x4;
typedef __attribute__((ext_vector_type(8))) short bfrag;   // 8 bf16 = 4 VGPRs
typedef __attribute__((ext_vector_type(4))) short s16x4;   // 4 bf16 = 8B
typedef __attribute__((ext_vector_type(4))) float facc;    // 4 f32 accum

#define MFMA16(A,B,C) __builtin_amdgcn_mfma_f32_16x16x32_bf16(A,B,C,0,0,0)
#define EXP2(x) __builtin_amdgcn_exp2f(x)

// HW bf16 pack — T12 recipe: no builtin on gfx950, inline asm v_cvt_pk_bf16_f32
__device__ __forceinline__ unsigned pk2bf(float a, float b) {
    unsigned r;
    asm("v_cvt_pk_bf16_f32 %0, %1, %2" : "=v"(r) : "v"(a), "v"(b));
    return r;
}
__device__ __forceinline__ short f2bf(float a) {   // prep-only, manual RNE
    unsigned ua = __builtin_bit_cast(unsigned, a);
    ua = ua + 0x7fffu + ((ua >> 16) & 1u);
    return (short)(ua >> 16);
}
__device__ __forceinline__ float bf2f(short s) {
    unsigned u = ((unsigned)(unsigned short)s) << 16;
    return __builtin_bit_cast(float, u);
}
// XOR swizzle (T2/G4)
__device__ __forceinline__ int sw256(int row, int cb) { return row * 256 + (cb ^ ((row & 7) << 4)); }
__device__ __forceinline__ int sw128(int row, int cb) { return row * 128 + (cb ^ ((row & 7) << 4)); }

// ws (shorts): Wq_frag 0 | Wk_frag 16384 | Wv_frag 32768 | Wp_frag 49152 |
//              RB_frag (×log2e) 65536 | cmb_frag 81920 (if ws_size permits)
__global__ void prep_w(const float* __restrict__ Wq, const float* __restrict__ Wk,
                       const float* __restrict__ Wv, const float* __restrict__ Wp,
                       const float* __restrict__ relb, short* __restrict__ ws)
{
    int t = blockIdx.x * 256 + threadIdx.x;
    if (t >= 16384) return;
    int e = t & 7, lane = (t >> 3) & 63, ks = (t >> 9) & 3, tile = t >> 11;
    int row = tile * 16 + (lane & 15);
    int col = ks * 32 + (lane >> 4) * 8 + e;
    int src = row * 128 + col;
    ws[t]         = f2bf(Wq[src]);
    ws[16384 + t] = f2bf(Wk[src]);
    ws[32768 + t] = f2bf(Wv[src]);
    ws[49152 + t] = f2bf(Wp[src]);
    int e2 = t & 3, lane2 = (t >> 2) & 63, mt = (t >> 8) & 3, rt = (t >> 10) & 3, h = t >> 12;
    int r = rt * 16 + (lane2 & 15);
    int m = mt * 16 + (lane2 >> 4) * 4 + e2;
    float v = 0.f;
    if (r < NTOK && m < NTOK) {
        int idx = ((r / 7 - m / 7) + 6) * 13 + ((r % 7) - (m % 7) + 6);
        v = relb[idx * 4 + h] * LOG2E;
    }
    ws[65536 + t] = f2bf(v);
}

// cmb_frag[w][h][rt][mt][lane][4] = (mask + rel_bias)*log2e, pads = -1e30 (bf16)
__global__ void prep_cmb(const float* __restrict__ mask, const float* __restrict__ relb,
                         short* __restrict__ cmb)
{
    int t = blockIdx.x * 256 + threadIdx.x;            // 16,777,216 entries
    int e = t & 3, lane = (t >> 2) & 63, mt = (t >> 8) & 3, rt = (t >> 10) & 3;
    int h = (t >> 12) & 3, w = t >> 14;
    int r = rt * 16 + (lane & 15);
    int m = mt * 16 + (lane >> 4) * 4 + e;
    float v = -1e30f;
    if (r < NTOK && m < NTOK) {
        int idx = ((r / 7 - m / 7) + 6) * 13 + ((r % 7) - (m % 7) + 6);
        v = (mask[w * (NTOK * NTOK) + r * NTOK + m] + relb[idx * 4 + h]) * LOG2E;
    }
    cmb[t] = f2bf(v);
}

// P placement inside q∪k (barrier-protected; XOR crosses 64B strips — bijective per row)
__device__ __forceinline__ char* pstrip(char* smem_, int wid, int r, int mb) {
    return smem_ + ((mb >> 6) << 14) + r * 256 + ((wid * 64 + (mb & 63)) ^ ((r & 7) << 4));
}

// ============ persistent kernel: 512 blocks (2/CU) × 32 windows each ============
// LDS 64KB: q[64][256B] @0 | k @16K | vT[128][128B] @32K | x @48K (r4)
// P overlays q∪k after B_P; att overlays qbuf after B1; x(w+1) staged into r4 at P3-time.
// Barriers/window: B_P (QK^T done -> P + x-write), B1 (PV done -> att), B2 (att staged),
//                  B3 (proj att-reads done -> next window q/k/vT writes).
__global__ __launch_bounds__(256, 2) void swin_fwd_p(
    const float* __restrict__ x,
    const float* __restrict__ bq, const float* __restrict__ bk,
    const float* __restrict__ bv, const float* __restrict__ bp,
    const short* __restrict__ wqf, const short* __restrict__ wkf,
    const short* __restrict__ wvf, const short* __restrict__ wpf,
    const short* __restrict__ cmbf, float* __restrict__ out)
{
    extern __shared__ char smem[];
    char* qbuf  = smem;
    char* kbuf  = smem + 16384;
    char* vtbuf = smem + 32768;
    char* r4    = smem + 49152;

    const int b = blockIdx.x;
    const int tid = threadIdx.x;
    const int wid = tid >> 6;
    const int lane = tid & 63;
    const int l16 = lane & 15;
    const int lg = lane >> 4;

    // persistent biases (26 VGPRs)
    float bqv[2][4], bkv[2][4], bpv[2][4], bvv2[2];
    #pragma unroll
    for (int mt = 0; mt < 2; ++mt) {
        #pragma unroll
        for (int j = 0; j < 4; ++j) {
            int o = wid * 32 + mt * 16 + lg * 4 + j;
            bqv[mt][j] = bq[o]; bkv[mt][j] = bk[o]; bpv[mt][j] = bp[o];
        }
        bvv2[mt] = bv[wid * 32 + mt * 16 + l16];
    }

    // first window's weight frags (reloaded each window; laundered ptrs stop hoisting)
    bfrag aq[2][4], ak[2][4], av[2][4];
    {
        const short* wq_i = wqf; const short* wk_i = wkf; const short* wv_i = wvf;
        asm volatile("" : "+s"(wq_i), "+s"(wk_i), "+s"(wv_i));
        #pragma unroll
        for (int mt = 0; mt < 2; ++mt)
            #pragma unroll
            for (int ks = 0; ks < 4; ++ks) {
                int fi = (((wid * 2 + mt) * 4 + ks) * 64 + lane) * 8;
                aq[mt][ks] = *(const bfrag*)(wq_i + fi);
                ak[mt][ks] = *(const bfrag*)(wk_i + fi);
                av[mt][ks] = *(const bfrag*)(wv_i + fi);
            }
    }

    // prologue: stage x(b) -> r4; pad rows zeroed ONCE (never rewritten)
    f32x4 xr[7];
    {
        const float* xw0 = x + (size_t)b * 6272;
        #pragma unroll
        for (int ii = 0; ii < 7; ++ii) {
            int i4 = ii * 256 + tid;
            if (i4 < 1568) xr[ii] = *(const f32x4*)(xw0 + i4 * 4);
        }
        #pragma unroll
        for (int ii = 0; ii < 7; ++ii) {
            int i4 = ii * 256 + tid;
            if (i4 < 1568) {
                int tok = i4 >> 5, col = (i4 & 31) * 4;
                u32x2 w; w.x = pk2bf(xr[ii].x, xr[ii].y); w.y = pk2bf(xr[ii].z, xr[ii].w);
                *(u32x2*)(r4 + sw256(tok, col * 2)) = w;
            }
        }
        if (tid < 240) { u32x4 z = {0, 0, 0, 0}; *(u32x4*)(r4 + 49 * 256 + tid * 16) = z; }
    }
    __syncthreads();   // B0 (once): x(b) staged

    #pragma unroll 1
    for (int it = 0; it < 32; ++it) {
        const int win = b + (it << 9);

        // issue x prefetch for next window (HBM latency hides under P1..P2)
        {
            const float* xn = x + (size_t)((win + 512) & 16383) * 6272;
            #pragma unroll
            for (int ii = 0; ii < 7; ++ii) {
                int i4 = ii * 256 + tid;
                if (i4 < 1568) xr[ii] = *(const f32x4*)(xn + i4 * 4);
            }
        }

        // ---- P1: QKV. q,k -> row-major strips; v -> vT rows (packed 8B stores)
        {
            #pragma unroll
            for (int nt = 0; nt < 4; ++nt) {
                bfrag bx[4];
                #pragma unroll
                for (int ks = 0; ks < 4; ++ks)
                    bx[ks] = *(const bfrag*)(r4 + sw256(nt * 16 + l16, (ks * 32 + lg * 8) * 2));
                facc accq[2] = {{0,0,0,0},{0,0,0,0}};
                facc acck[2] = {{0,0,0,0},{0,0,0,0}};
                facc accv[2] = {{0,0,0,0},{0,0,0,0}};
                __builtin_amdgcn_s_setprio(1);
                #pragma unroll
                for (int ks = 0; ks < 4; ++ks)
                    #pragma unroll
                    for (int mt = 0; mt < 2; ++mt) {
                        accq[mt] = MFMA16(aq[mt][ks], bx[ks], accq[mt]);
                        acck[mt] = MFMA16(ak[mt][ks], bx[ks], acck[mt]);
                        accv[mt] = MFMA16(bx[ks], av[mt][ks], accv[mt]);
                    }
                __builtin_amdgcn_s_setprio(0);
                int tok = nt * 16 + l16;
                #pragma unroll
                for (int mt = 0; mt < 2; ++mt) {
                    int o0 = wid * 32 + mt * 16 + lg * 4;
                    u32x2 wq2, wk2, wv2;
                    wq2.x = pk2bf((accq[mt][0] + bqv[mt][0]) * SCALE2, (accq[mt][1] + bqv[mt][1]) * SCALE2);
                    wq2.y = pk2bf((accq[mt][2] + bqv[mt][2]) * SCALE2, (accq[mt][3] + bqv[mt][3]) * SCALE2);
                    wk2.x = pk2bf(acck[mt][0] + bkv[mt][0], acck[mt][1] + bkv[mt][1]);
                    wk2.y = pk2bf(acck[mt][2] + bkv[mt][2], acck[mt][3] + bkv[mt][3]);
                    *(u32x2*)(qbuf + sw256(tok, o0 * 2)) = wq2;
                    *(u32x2*)(kbuf + sw256(tok, o0 * 2)) = wk2;
                    wv2.x = pk2bf(accv[mt][0] + bvv2[mt], accv[mt][1] + bvv2[mt]);
                    wv2.y = pk2bf(accv[mt][2] + bvv2[mt], accv[mt][3] + bvv2[mt]);
                    *(u32x2*)(vtbuf + sw128(wid * 32 + mt * 16 + l16, (nt * 16 + lg * 4) * 2)) = wv2;
                }
            }
        }
        // NO barrier: q/k/vT read back by the writing wave (same addresses)

        // ---- P2: QK^T (S^T = k·qT) from own strips
        facc s[4][4];
        {
            bfrag ka[4], qb[4];
            int cb = (wid * 32 + lg * 8) * 2;
            #pragma unroll
            for (int t = 0; t < 4; ++t) {
                ka[t] = *(const bfrag*)(kbuf + sw256(t * 16 + l16, cb));
                qb[t] = *(const bfrag*)(qbuf + sw256(t * 16 + l16, cb));
            }
            __builtin_amdgcn_s_setprio(1);
            #pragma unroll
            for (int mt = 0; mt < 4; ++mt)
                #pragma unroll
                for (int rt = 0; rt < 4; ++rt) {
                    facc z = {0, 0, 0, 0};
                    s[mt][rt] = MFMA16(ka[mt], qb[rt], z);
                }
            __builtin_amdgcn_s_setprio(0);
        }
        __syncthreads();   // B_P: QK^T reads done; x(win) dead everywhere

        // ---- x(w+1) -> r4 (r4 free from here until next-iteration P1)
        {
            #pragma unroll
            for (int ii = 0; ii < 7; ++ii) {
                int i4 = ii * 256 + tid;
                if (i4 < 1568) {
                    int tok = i4 >> 5, col = (i4 & 31) * 4;
                    u32x2 w; w.x = pk2bf(xr[ii].x, xr[ii].y); w.y = pk2bf(xr[ii].z, xr[ii].w);
                    *(u32x2*)(r4 + sw256(tok, col * 2)) = w;
                }
            }
        }

        // ---- P3: softmax over key m (log2 domain); cmb slice is L2-resident
        float rs4[4];
        {
            const short* cw = cmbf + ((size_t)((win & 1023) * 4 + wid) << 12);
            #pragma unroll
            for (int rt = 0; rt < 4; ++rt) {
                float lgt[4][4];
                float mx = -3e38f;
                #pragma unroll
                for (int mt = 0; mt < 4; ++mt) {
                    s16x4 b4 = *(const s16x4*)(cw + ((rt * 4 + mt) << 8) + lane * 4);
                    #pragma unroll
                    for (int j = 0; j < 4; ++j) {
                        float v = s[mt][rt][j] + bf2f(b4[j]);
                        lgt[mt][j] = v;
                        mx = fmaxf(mx, v);
                    }
                }
                mx = fmaxf(mx, __shfl_xor(mx, 16));
                mx = fmaxf(mx, __shfl_xor(mx, 32));
                float sum = 0.f;
                u32x2 pw[4];
                #pragma unroll
                for (int mt = 0; mt < 4; ++mt) {
                    float p0 = EXP2(lgt[mt][0] - mx);
                    float p1 = EXP2(lgt[mt][1] - mx);
                    float p2 = EXP2(lgt[mt][2] - mx);
                    float p3 = EXP2(lgt[mt][3] - mx);
                    sum += (p0 + p1) + (p2 + p3);
                    pw[mt].x = pk2bf(p0, p1);
                    pw[mt].y = pk2bf(p2, p3);
                }
                sum += __shfl_xor(sum, 16);
                sum += __shfl_xor(sum, 32);
                rs4[rt] = __builtin_amdgcn_rcpf(sum);
                int r = rt * 16 + l16;
                #pragma unroll
                for (int mt = 0; mt < 4; ++mt)
                    *(u32x2*)pstrip(smem, wid, r, mt * 32 + lg * 8) = pw[mt];
            }
        }
        // NO barrier: P read back by the writing wave

        // ---- P4: PV swapped: outT[c][r] = vT · P
        facc o2[2][4];
        {
            #pragma unroll
            for (int ct = 0; ct < 2; ++ct)
                #pragma unroll
                for (int rt = 0; rt < 4; ++rt) o2[ct][rt] = (facc){0, 0, 0, 0};
            #pragma unroll
            for (int ks = 0; ks < 2; ++ks) {
                bfrag avf[2], pb[4];
                #pragma unroll
                for (int ct = 0; ct < 2; ++ct)
                    avf[ct] = *(const bfrag*)(vtbuf + sw128(wid * 32 + ct * 16 + l16, (ks * 32 + lg * 8) * 2));
                #pragma unroll
                for (int rt = 0; rt < 4; ++rt)
                    pb[rt] = *(const bfrag*)pstrip(smem, wid, rt * 16 + l16, ks * 64 + lg * 16);
                __builtin_amdgcn_s_setprio(1);
                #pragma unroll
                for (int ct = 0; ct < 2; ++ct)
                    #pragma unroll
                    for (int rt = 0; rt < 4; ++rt)
                        o2[ct][rt] = MFMA16(avf[ct], pb[rt], o2[ct][rt]);
                __builtin_amdgcn_s_setprio(0);
            }
        }
        // issue proj-weight frags (L2-hot; in flight across B1/att/B2)
        bfrag ap[2][4];
        {
            const short* wp_i = wpf;
            asm volatile("" : "+s"(wp_i));
            #pragma unroll
            for (int mt = 0; mt < 2; ++mt)
                #pragma unroll
                for (int ks = 0; ks < 4; ++ks)
                    ap[mt][ks] = *(const bfrag*)(wp_i + (((wid * 2 + mt) * 4 + ks) * 64 + lane) * 8);
        }
        __syncthreads();   // B1: all PV reads of P done -> att may overwrite qbuf
        {
            #pragma unroll
            for (int ct = 0; ct < 2; ++ct) {
                int c0 = wid * 32 + ct * 16 + lg * 4;
                #pragma unroll
                for (int rt = 0; rt < 4; ++rt) {
                    int r = rt * 16 + l16;
                    float sc = rs4[rt];
                    u32x2 w;
                    w.x = pk2bf(o2[ct][rt][0] * sc, o2[ct][rt][1] * sc);
                    w.y = pk2bf(o2[ct][rt][2] * sc, o2[ct][rt][3] * sc);
                    *(u32x2*)(qbuf + sw256(r, c0 * 2)) = w;
                }
            }
        }
        __syncthreads();   // B2: att staged -> proj reads

        // ---- P5: proj: D[o][tok] = Wp · att^T; contiguous f32x4 stores
        {
            facc acco[2][4];
            #pragma unroll
            for (int mt = 0; mt < 2; ++mt)
                #pragma unroll
                for (int tt = 0; tt < 4; ++tt) acco[mt][tt] = (facc){0, 0, 0, 0};
            #pragma unroll
            for (int tt = 0; tt < 4; ++tt) {
                bfrag ba[4];
                #pragma unroll
                for (int ks = 0; ks < 4; ++ks)
                    ba[ks] = *(const bfrag*)(qbuf + sw256(tt * 16 + l16, (ks * 32 + lg * 8) * 2));
                __builtin_amdgcn_s_setprio(1);
                #pragma unroll
                for (int ks = 0; ks < 4; ++ks)
                    #pragma unroll
                    for (int mt = 0; mt < 2; ++mt)
                        acco[mt][tt] = MFMA16(ap[mt][ks], ba[ks], acco[mt][tt]);
                __builtin_amdgcn_s_setprio(0);
            }
            float* ow = out + (size_t)win * 6272;
            #pragma unroll
            for (int tt = 0; tt < 4; ++tt) {
                int tok = tt * 16 + l16;
                if (tok < NTOK) {
                    #pragma unroll
                    for (int mt = 0; mt < 2; ++mt) {
                        int o0 = wid * 32 + mt * 16 + lg * 4;
                        f32x4 w;
                        w.x = acco[mt][tt][0] + bpv[mt][0];
                        w.y = acco[mt][tt][1] + bpv[mt][1];
                        w.z = acco[mt][tt][2] + bpv[mt][2];
                        w.w = acco[mt][tt][3] + bpv[mt][3];
                        *(f32x4*)(ow + tok * 128 + o0) = w;
                    }
                }
            }
        }

        // refill QKV weight frags for the next window (in flight across B3)
        {
            const short* wq_i = wqf; const short* wk_i = wkf; const short* wv_i = wvf;
            asm volatile("" : "+s"(wq_i), "+s"(wk_i), "+s"(wv_i));
            #pragma unroll
            for (int mt = 0; mt < 2; ++mt)
                #pragma unroll
                for (int ks = 0; ks < 4; ++ks) {
                    int fi = (((wid * 2 + mt) * 4 + ks) * 64 + lane) * 8;
                    aq[mt][ks] = *(const bfrag*)(wq_i + fi);
                    ak[mt][ks] = *(const bfrag*)(wk_i + fi);
                    av[mt][ks] = *(const bfrag*)(wv_i + fi);
                }
        }
        __syncthreads();   // B3: proj att-reads done -> next P1 may overwrite q∪k/vT
    }
}

// ============ fallback (no cmb in ws): round-6 structure, grid 16384 ============
__global__ __launch_bounds__(256, 2) void swin_fwd_fb(
    const float* __restrict__ x, const float* __restrict__ mask,
    const float* __restrict__ bq, const float* __restrict__ bk,
    const float* __restrict__ bv, const float* __restrict__ bp,
    const short* __restrict__ wqf, const short* __restrict__ wkf,
    const short* __restrict__ wvf, const short* __restrict__ wpf,
    const short* __restrict__ rbf, float* __restrict__ out)
{
    extern __shared__ char smem[];
    char* qbuf  = smem;
    char* kbuf  = smem + 16384;
    char* vtbuf = smem + 32768;
    char* r4    = smem + 49152;

    const int win = blockIdx.x;
    const int tid = threadIdx.x;
    const int wid = tid >> 6;
    const int lane = tid & 63;
    const int l16 = lane & 15;
    const int lg = lane >> 4;

    {
        const float* xw = x + (size_t)win * 6272;
        #pragma unroll
        for (int i = 0; i < 7; ++i) {
            int i4 = i * 256 + tid;
            if (i4 < 1568) {
                f32x4 f = *(const f32x4*)(xw + i4 * 4);
                int tok = i4 >> 5, col = (i4 & 31) * 4;
                u32x2 w; w.x = pk2bf(f.x, f.y); w.y = pk2bf(f.z, f.w);
                *(u32x2*)(r4 + sw256(tok, col * 2)) = w;
            }
        }
        if (tid < 240) { u32x4 z = {0, 0, 0, 0}; *(u32x4*)(r4 + 49 * 256 + tid * 16) = z; }
    }
    bfrag aq[2][4], ak[2][4], av[2][4];
    float bqv[2][4], bkv[2][4], bvv2[2];
    #pragma unroll
    for (int mt = 0; mt < 2; ++mt) {
        #pragma unroll
        for (int ks = 0; ks < 4; ++ks) {
            int fi = (((wid * 2 + mt) * 4 + ks) * 64 + lane) * 8;
            aq[mt][ks] = *(const bfrag*)(wqf + fi);
            ak[mt][ks] = *(const bfrag*)(wkf + fi);
            av[mt][ks] = *(const bfrag*)(wvf + fi);
        }
        #pragma unroll
        for (int j = 0; j < 4; ++j) {
            int o = wid * 32 + mt * 16 + lg * 4 + j;
            bqv[mt][j] = bq[o]; bkv[mt][j] = bk[o];
        }
        bvv2[mt] = bv[wid * 32 + mt * 16 + l16];
    }
    __syncthreads();

    {
        #pragma unroll
        for (int nt = 0; nt < 4; ++nt) {
            bfrag bx[4];
            #pragma unroll
            for (int ks = 0; ks < 4; ++ks)
                bx[ks] = *(const bfrag*)(r4 + sw256(nt * 16 + l16, (ks * 32 + lg * 8) * 2));
            facc accq[2] = {{0,0,0,0},{0,0,0,0}};
            facc acck[2] = {{0,0,0,0},{0,0,0,0}};
            facc accv[2] = {{0,0,0,0},{0,0,0,0}};
            #pragma unroll
            for (int ks = 0; ks < 4; ++ks)
                #pragma unroll
                for (int mt = 0; mt < 2; ++mt) {
                    accq[mt] = MFMA16(aq[mt][ks], bx[ks], accq[mt]);
                    acck[mt] = MFMA16(ak[mt][ks], bx[ks], acck[mt]);
                    accv[mt] = MFMA16(bx[ks], av[mt][ks], accv[mt]);
                }
            int tok = nt * 16 + l16;
            #pragma unroll
            for (int mt = 0; mt < 2; ++mt) {
                int o0 = wid * 32 + mt * 16 + lg * 4;
                u32x2 wq2, wk2, wv2;
                wq2.x = pk2bf((accq[mt][0] + bqv[mt][0]) * SCALE2, (accq[mt][1] + bqv[mt][1]) * SCALE2);
                wq2.y = pk2bf((accq[mt][2] + bqv[mt][2]) * SCALE2, (accq[mt][3] + bqv[mt][3]) * SCALE2);
                wk2.x = pk2bf(acck[mt][0] + bkv[mt][0], acck[mt][1] + bkv[mt][1]);
                wk2.y = pk2bf(acck[mt][2] + bkv[mt][2], acck[mt][3] + bkv[mt][3]);
                *(u32x2*)(qbuf + sw256(tok, o0 * 2)) = wq2;
                *(u32x2*)(kbuf + sw256(tok, o0 * 2)) = wk2;
                wv2.x = pk2bf(accv[mt][0] + bvv2[mt], accv[mt][1] + bvv2[mt]);
                wv2.y = pk2bf(accv[mt][2] + bvv2[mt], accv[mt][3] + bvv2[mt]);
                *(u32x2*)(vtbuf + sw128(wid * 32 + mt * 16 + l16, (nt * 16 + lg * 4) * 2)) = wv2;
            }
        }
    }
    facc s[4][4];
    {
        bfrag ka[4], qb[4];
        int cb = (wid * 32 + lg * 8) * 2;
        #pragma unroll
        for (int t = 0; t < 4; ++t) {
            ka[t] = *(const bfrag*)(kbuf + sw256(t * 16 + l16, cb));
            qb[t] = *(const bfrag*)(qbuf + sw256(t * 16 + l16, cb));
        }
        #pragma unroll
        for (int mt = 0; mt < 4; ++mt)
            #pragma unroll
            for (int rt = 0; rt < 4; ++rt) {
                facc z = {0, 0, 0, 0};
                s[mt][rt] = MFMA16(ka[mt], qb[rt], z);
            }
    }
    __syncthreads();   // x dead, q/k reads done
    {
        const float* mw = mask + (size_t)(win & 1023) * (NTOK * NTOK);
        #pragma unroll
        for (int i = 0; i < 16; ++i) {
            int flat = i * 256 + tid;
            int r = flat >> 6, m = flat & 63;
            float v = -1e30f;
            if (r < NTOK && m < NTOK) v = mw[r * 49 + m] * LOG2E;
            *(float*)(r4 + sw256(r, m * 4)) = v;
        }
    }
    __syncthreads();
    float rs4[4];
    {
        #pragma unroll
        for (int rt = 0; rt < 4; ++rt) {
            int r = rt * 16 + l16;
            float lgt[4][4];
            float mx = -3e38f;
            #pragma unroll
            for (int mt = 0; mt < 4; ++mt) {
                s16x4 b4 = *(const s16x4*)(rbf + ((wid * 16 + rt * 4 + mt) * 64 + lane) * 4);
                f32x4 mk = *(const f32x4*)(r4 + sw256(r, (mt * 16 + lg * 4) * 4));
                #pragma unroll
                for (int j = 0; j < 4; ++j) {
                    float v = s[mt][rt][j] + bf2f(b4[j]) + mk[j];
                    lgt[mt][j] = v;
                    mx = fmaxf(mx, v);
                }
            }
            mx = fmaxf(mx, __shfl_xor(mx, 16));
            mx = fmaxf(mx, __shfl_xor(mx, 32));
            float sum = 0.f;
            u32x2 pw[4];
            #pragma unroll
            for (int mt = 0; mt < 4; ++mt) {
                float p0 = EXP2(lgt[mt][0] - mx);
                float p1 = EXP2(lgt[mt][1] - mx);
                float p2 = EXP2(lgt[mt][2] - mx);
                float p3 = EXP2(lgt[mt][3] - mx);
                sum += (p0 + p1) + (p2 + p3);
                pw[mt].x = pk2bf(p0, p1);
                pw[mt].y = pk2bf(p2, p3);
            }
            sum += __shfl_xor(sum, 16);
            sum += __shfl_xor(sum, 32);
            rs4[rt] = __builtin_amdgcn_rcpf(sum);
            #pragma unroll
            for (int mt = 0; mt < 4; ++mt)
                *(u32x2*)pstrip(smem, wid, r, mt * 32 + lg * 8) = pw[mt];
        }
    }
    facc o2[2][4];
    {
        #pragma unroll
        for (int ct = 0; ct < 2; ++ct)
            #pragma unroll
            for (int rt = 0; rt < 4; ++rt) o2[ct][rt] = (facc){0, 0, 0, 0};
        #pragma unroll
        for (int ks = 0; ks < 2; ++ks) {
            bfrag avf[2], pb[4];
            #pragma unroll
            for (int ct = 0; ct < 2; ++ct)
                avf[ct] = *(const bfrag*)(vtbuf + sw128(wid * 32 + ct * 16 + l16, (ks * 32 + lg * 8) * 2));
            #pragma unroll
            for (int rt = 0; rt < 4; ++rt)
                pb[rt] = *(const bfrag*)pstrip(smem, wid, rt * 16 + l16, ks * 64 + lg * 16);
            #pragma unroll
            for (int ct = 0; ct < 2; ++ct)
                #pragma unroll
                for (int rt = 0; rt < 4; ++rt)
                    o2[ct][rt] = MFMA16(avf[ct], pb[rt], o2[ct][rt]);
        }
    }
    bfrag ap[2][4];
    float bpv[2][4];
    #pragma unroll
    for (int mt = 0; mt < 2; ++mt) {
        #pragma unroll
        for (int ks = 0; ks < 4; ++ks)
            ap[mt][ks] = *(const bfrag*)(wpf + (((wid * 2 + mt) * 4 + ks) * 64 + lane) * 8);
        #pragma unroll
        for (int j = 0; j < 4; ++j)
            bpv[mt][j] = bp[wid * 32 + mt * 16 + lg * 4 + j];
    }
    __syncthreads();
    {
        #pragma unroll
        for (int ct = 0; ct < 2; ++ct) {
            int c0 = wid * 32 + ct * 16 + lg * 4;
            #pragma unroll
            for (int rt = 0; rt < 4; ++rt) {
                int r = rt * 16 + l16;
                float sc = rs4[rt];
                u32x2 w;
                w.x = pk2bf(o2[ct][rt][0] * sc, o2[ct][rt][1] * sc);
                w.y = pk2bf(o2[ct][rt][2] * sc, o2[ct][rt][3] * sc);
                *(u32x2*)(r4 + sw256(r, c0 * 2)) = w;
            }
        }
    }
    __syncthreads();
    {
        facc acco[2][4];
        #pragma unroll
        for (int mt = 0; mt < 2; ++mt)
            #pragma unroll
            for (int tt = 0; tt < 4; ++tt) acco[mt][tt] = (facc){0, 0, 0, 0};
        #pragma unroll
        for (int tt = 0; tt < 4; ++tt) {
            bfrag ba[4];
            #pragma unroll
            for (int ks = 0; ks < 4; ++ks)
                ba[ks] = *(const bfrag*)(r4 + sw256(tt * 16 + l16, (ks * 32 + lg * 8) * 2));
            #pragma unroll
            for (int ks = 0; ks < 4; ++ks)
                #pragma unroll
                for (int mt = 0; mt < 2; ++mt)
                    acco[mt][tt] = MFMA16(ap[mt][ks], ba[ks], acco[mt][tt]);
        }
        float* ow = out + (size_t)win * 6272;
        #pragma unroll
        for (int tt = 0; tt < 4; ++tt) {
            int tok = tt * 16 + l16;
            if (tok < NTOK) {
                #pragma unroll
                for (int mt = 0; mt < 2; ++mt) {
                    int o0 = wid * 32 + mt * 16 + lg * 4;
                    f32x4 w;
                    w.x = acco[mt][tt][0] + bpv[mt][0];
                    w.y = acco[mt][tt][1] + bpv[mt][1];
                    w.z = acco[mt][tt][2] + bpv[mt][2];
                    w.w = acco[mt][tt][3] + bpv[mt][3];
                    *(f32x4*)(ow + tok * 128 + o0) = w;
                }
            }
        }
    }
}

extern "C" void kernel_launch(void* const* d_in, const int* in_sizes, int n_in,
                              void* d_out, int out_size, void* d_ws, size_t ws_size,
                              hipStream_t stream)
{
    const float* x    = (const float*)d_in[0];
    const float* mask = (const float*)d_in[1];
    const float* Wq   = (const float*)d_in[2];
    const float* bq   = (const float*)d_in[3];
    const float* Wk   = (const float*)d_in[4];
    const float* bk   = (const float*)d_in[5];
    const float* Wv   = (const float*)d_in[6];
    const float* bv   = (const float*)d_in[7];
    const float* Wp   = (const float*)d_in[8];
    const float* bp   = (const float*)d_in[9];
    const float* rlb  = (const float*)d_in[10];
    short* ws = (short*)d_ws;
    short* cmb = ws + 81920;
    const size_t need = ((size_t)81920 + (size_t)16777216) * 2;
    const bool use_cmb = ws_size >= need;

    prep_w<<<64, 256, 0, stream>>>(Wq, Wk, Wv, Wp, rlb, ws);
    if (use_cmb) {
        prep_cmb<<<65536, 256, 0, stream>>>(mask, rlb, cmb);
        swin_fwd_p<<<512, 256, 65536, stream>>>(x, bq, bk, bv, bp,
            ws, ws + 16384, ws + 32768, ws + 49152, cmb, (float*)d_out);
    } else {
        swin_fwd_fb<<<16384, 256, 65536, stream>>>(x, mask, bq, bk, bv, bp,
            ws, ws + 16384, ws + 32768, ws + 49152, ws + 65536, (float*)d_out);
    }
}